// Round 1
// baseline (352.093 us; speedup 1.0000x reference)
//
#include <hip/hip_runtime.h>
#include <hip/hip_bf16.h>
#include <stdint.h>

#define EPS 1e-5f
#define NOUT 2338   // 2048+256+32+1+1 output cols per batch row

typedef __bf16 bf16x8 __attribute__((ext_vector_type(8)));
typedef float f32x4 __attribute__((ext_vector_type(4)));
typedef unsigned short u16;

__device__ __forceinline__ u16 f2bf_bits(float f) {
  uint32_t u = __builtin_bit_cast(uint32_t, f);
  u += 0x7FFFu + ((u >> 16) & 1u);   // RNE
  return (u16)(u >> 16);
}

__device__ __forceinline__ uint32_t pack2(float lo, float hi) {
  return (uint32_t)f2bf_bits(lo) | ((uint32_t)f2bf_bits(hi) << 16);
}

// ---------------- kernel 0: x [256][3008] f32 -> bf16 ----------------
__global__ __launch_bounds__(256) void cvt_x_kernel(const float* __restrict__ x,
                                                    u16* __restrict__ xb) {
  const size_t i = (size_t)blockIdx.x * 256 + threadIdx.x;  // 8-elem chunk, 96256 total
  const float4* src = (const float4*)x + i * 2;
  float4 a = src[0], b = src[1];
  uint4 o;
  o.x = pack2(a.x, a.y);
  o.y = pack2(a.z, a.w);
  o.z = pack2(b.x, b.y);
  o.w = pack2(b.z, b.w);
  ((uint4*)xb)[i] = o;
}

// ---------------- kernel 1: leaf GEMM  h[tg][b] = sum_n gW[tg][n]*x[b][n] + gb[tg]
// C [20480 x 256] = W[20480 x 3008] * X^T.  16x16x32 bf16 MFMA.
// block = 128 thr (2 waves), BN=32 cols/block (16/wave), full batch 256 (16 m-tiles).
__global__ __launch_bounds__(128) void gemm_leaf(const float* __restrict__ W,
                                                 const float* __restrict__ gb,
                                                 const u16* __restrict__ XB,
                                                 float* __restrict__ hout) {
  // LDS X tile: [kb(4)][m(256)][e(8)] bf16 = 16 KB, staged fresh each k-step
  __shared__ __align__(16) u16 xl[1024 * 8];
  const int tid = threadIdx.x;
  const int wv = tid >> 6;        // 0..1
  const int lane = tid & 63;
  const int lquad = lane >> 4;    // k-group 0..3
  const int lmod = lane & 15;
  const int n0 = blockIdx.x * 32;
  const int arow = n0 + wv * 16 + lmod;          // A-frag row (tg col of output)

  f32x4 acc[16];
#pragma unroll
  for (int i = 0; i < 16; ++i) acc[i] = (f32x4){0.f, 0.f, 0.f, 0.f};

  const float* wp = W + (size_t)arow * 3008 + lquad * 8;

  for (int ks = 0; ks < 94; ++ks) {
    const int k0 = ks * 32;
    __syncthreads();   // previous tile consumed
    // stage XB[0:256][k0:k0+32] -> xl ; 1024 16B chunks, 8 per thread
#pragma unroll
    for (int p = 0; p < 8; ++p) {
      const int c = p * 128 + wv * 64;           // wave-uniform chunk base
      const int kb = c >> 8;                      // uniform within wave-pass
      const int m = (c & 255) + lane;
      const u16* src = XB + (size_t)m * 3008 + k0 + kb * 8;
      u16* dst = xl + (size_t)c * 8;
      __builtin_amdgcn_global_load_lds((const __attribute__((address_space(1))) void*)src,
                                       (__attribute__((address_space(3))) void*)dst,
                                       16, 0, 0);
    }
    // A fragment: W row arow, k = k0 + lquad*8 + e  (8 consecutive fp32 -> bf16)
    const float4* ap = (const float4*)(wp + k0);
    float4 wa = ap[0], wb = ap[1];
    union { u16 u[8]; bf16x8 v; } af;
    af.u[0] = f2bf_bits(wa.x); af.u[1] = f2bf_bits(wa.y);
    af.u[2] = f2bf_bits(wa.z); af.u[3] = f2bf_bits(wa.w);
    af.u[4] = f2bf_bits(wb.x); af.u[5] = f2bf_bits(wb.y);
    af.u[6] = f2bf_bits(wb.z); af.u[7] = f2bf_bits(wb.w);
    __syncthreads();   // staged data visible
#pragma unroll
    for (int mt = 0; mt < 16; ++mt) {
      const bf16x8 bfrag =
          *(const bf16x8*)(xl + ((size_t)lquad * 256 + mt * 16 + lmod) * 8);
      acc[mt] = __builtin_amdgcn_mfma_f32_16x16x32_bf16(af.v, bfrag, acc[mt], 0, 0, 0);
    }
  }
  // store: D row = n0 + wv*16 + lquad*4 + r, col = mt*16 + lmod
  const int r0 = n0 + wv * 16 + lquad * 4;
  float gb4[4];
#pragma unroll
  for (int r2 = 0; r2 < 4; ++r2) gb4[r2] = gb[r0 + r2];
#pragma unroll
  for (int mt = 0; mt < 16; ++mt) {
#pragma unroll
    for (int r2 = 0; r2 < 4; ++r2) {
      hout[(size_t)(r0 + r2) * 256 + mt * 16 + lmod] = acc[mt][r2] + gb4[r2];
    }
  }
}

// ---------------- per-level kernel: one term per block, batch = 256 threads
// yin layout: [prev_cols][256]; term t uses cols t*inl .. t*inl+inl-1
// z = tanh(hin @ w^T + bias); y = BN(z)*gamma+beta; aux = r*tanh(y.p + q)+s
__global__ __launch_bounds__(256) void level_kernel(
    const float* __restrict__ yin, const float* __restrict__ w,
    const float* __restrict__ bia, const float* __restrict__ gam,
    const float* __restrict__ bet, const float* __restrict__ p,
    const float* __restrict__ q, const float* __restrict__ r,
    const float* __restrict__ s, float* __restrict__ yout,
    float* __restrict__ out, int inl, int off) {
  const int t = blockIdx.x;
  const int b = threadIdx.x;
  __shared__ float wls[6 * 192];
  __shared__ float part[4][12];
  __shared__ float stats[12];  // mean[6], rstd[6]
  const float* wt = w + (size_t)t * 6 * inl;
  for (int i = b; i < 6 * inl; i += 256) wls[i] = wt[i];
  __syncthreads();

  float z[6];
#pragma unroll
  for (int h = 0; h < 6; ++h) z[h] = bia[t * 6 + h];
  const float* yp = yin + (size_t)t * inl * 256 + b;
  for (int i = 0; i < inl; ++i) {
    float v = yp[(size_t)i * 256];
#pragma unroll
    for (int h = 0; h < 6; ++h) z[h] = fmaf(v, wls[h * inl + i], z[h]);
  }
#pragma unroll
  for (int h = 0; h < 6; ++h) z[h] = tanhf(z[h]);

  // batch-norm stats over the 256 threads
  float sm[6], sq[6];
#pragma unroll
  for (int h = 0; h < 6; ++h) { sm[h] = z[h]; sq[h] = z[h] * z[h]; }
#pragma unroll
  for (int o = 32; o > 0; o >>= 1) {
#pragma unroll
    for (int h = 0; h < 6; ++h) {
      sm[h] += __shfl_down(sm[h], o);
      sq[h] += __shfl_down(sq[h], o);
    }
  }
  const int lane = b & 63, wvi = b >> 6;
  if (lane == 0) {
#pragma unroll
    for (int h = 0; h < 6; ++h) { part[wvi][h] = sm[h]; part[wvi][6 + h] = sq[h]; }
  }
  __syncthreads();
  if (b < 6) {
    float msum = part[0][b] + part[1][b] + part[2][b] + part[3][b];
    float qsum = part[0][6 + b] + part[1][6 + b] + part[2][6 + b] + part[3][6 + b];
    float m = msum * (1.f / 256.f);
    float var = qsum * (1.f / 256.f) - m * m;
    stats[b] = m;
    stats[6 + b] = rsqrtf(var + EPS);
  }
  __syncthreads();

  float a = q[t];
#pragma unroll
  for (int h = 0; h < 6; ++h) {
    float yy = (z[h] - stats[h]) * stats[6 + h] * gam[t * 6 + h] + bet[t * 6 + h];
    yout[((size_t)t * 6 + h) * 256 + b] = yy;
    a = fmaf(yy, p[t * 6 + h], a);
  }
  out[(size_t)b * NOUT + off + t] = tanhf(a) * r[t] + s[t];
}

// ---------------- final head: of = BN(tanh(yroot@fw^T+fb)); auxf -> out col 2337
__global__ __launch_bounds__(256) void final_kernel(
    const float* __restrict__ y3, const float* __restrict__ fw,
    const float* __restrict__ fb, const float* __restrict__ fg,
    const float* __restrict__ fe, const float* __restrict__ pw,
    const float* __restrict__ pb, const float* __restrict__ rw,
    const float* __restrict__ rb, float* __restrict__ out) {
  const int b = threadIdx.x;
  __shared__ float part[4][24];
  __shared__ float stats[24];  // mean[12], rstd[12]
  float yr[6];
#pragma unroll
  for (int h = 0; h < 6; ++h) yr[h] = y3[h * 256 + b];
  float z[12];
#pragma unroll
  for (int j = 0; j < 12; ++j) {
    float a = fb[j];
#pragma unroll
    for (int h = 0; h < 6; ++h) a = fmaf(yr[h], fw[j * 6 + h], a);
    z[j] = tanhf(a);
  }
  float sm[12], sq[12];
#pragma unroll
  for (int j = 0; j < 12; ++j) { sm[j] = z[j]; sq[j] = z[j] * z[j]; }
#pragma unroll
  for (int o = 32; o > 0; o >>= 1) {
#pragma unroll
    for (int j = 0; j < 12; ++j) {
      sm[j] += __shfl_down(sm[j], o);
      sq[j] += __shfl_down(sq[j], o);
    }
  }
  const int lane = b & 63, wvi = b >> 6;
  if (lane == 0) {
#pragma unroll
    for (int j = 0; j < 12; ++j) { part[wvi][j] = sm[j]; part[wvi][12 + j] = sq[j]; }
  }
  __syncthreads();
  if (b < 12) {
    float msum = part[0][b] + part[1][b] + part[2][b] + part[3][b];
    float qsum = part[0][12 + b] + part[1][12 + b] + part[2][12 + b] + part[3][12 + b];
    float m = msum * (1.f / 256.f);
    float var = qsum * (1.f / 256.f) - m * m;
    stats[b] = m;
    stats[12 + b] = rsqrtf(var + EPS);
  }
  __syncthreads();
  float a = pb[0];
#pragma unroll
  for (int j = 0; j < 12; ++j) {
    float of = (z[j] - stats[j]) * stats[12 + j] * fg[j] + fe[j];
    a = fmaf(of, pw[j], a);
  }
  out[(size_t)b * NOUT + 2337] = tanhf(a) * rw[0] + rb[0];
}

extern "C" void kernel_launch(void* const* d_in, const int* in_sizes, int n_in,
                              void* d_out, int out_size, void* d_ws, size_t ws_size,
                              hipStream_t stream) {
  const float* x  = (const float*)d_in[0];
  const float* gW = (const float*)d_in[1];
  const float* gb = (const float*)d_in[2];
  float* out = (float*)d_out;

  // workspace layout
  char* wsb = (char*)d_ws;
  u16* XB = (u16*)wsb;                               // 256*3008 bf16 = 1,540,096 B
  float* h0 = (float*)(wsb + 1540096);               // [20480][256]
  float* y0 = h0 + (size_t)20480 * 256;              // [12288][256]
  float* y1 = y0 + (size_t)12288 * 256;              // [1536][256]
  float* y2 = y1 + (size_t)1536 * 256;               // [192][256]
  float* y3 = y2 + (size_t)192 * 256;                // [6][256]

  cvt_x_kernel<<<dim3(376), dim3(256), 0, stream>>>(x, XB);
  gemm_leaf<<<dim3(640), dim3(128), 0, stream>>>(gW, gb, XB, h0);

  // levels: d_in index base 3 + 8*l : w,b,g,e,p,q,r,s
#define LV(base, yin, yout, inl, off, grid)                                           \
  level_kernel<<<dim3(grid), dim3(256), 0, stream>>>(                                 \
      yin, (const float*)d_in[base], (const float*)d_in[base + 1],                    \
      (const float*)d_in[base + 2], (const float*)d_in[base + 3],                     \
      (const float*)d_in[base + 4], (const float*)d_in[base + 5],                     \
      (const float*)d_in[base + 6], (const float*)d_in[base + 7], yout, out, inl, off)

  LV(3,  h0, y0, 10,  0,    2048);
  LV(11, y0, y1, 48,  2048, 256);
  LV(19, y1, y2, 48,  2304, 32);
  LV(27, y2, y3, 192, 2336, 1);
#undef LV

  final_kernel<<<dim3(1), dim3(256), 0, stream>>>(
      y3, (const float*)d_in[35], (const float*)d_in[36], (const float*)d_in[37],
      (const float*)d_in[38], (const float*)d_in[39], (const float*)d_in[40],
      (const float*)d_in[41], (const float*)d_in[42], out);
}

// Round 4
// 211.240 us; speedup vs baseline: 1.6668x; 1.6668x over previous
//
#include <hip/hip_runtime.h>
#include <hip/hip_bf16.h>
#include <stdint.h>

#define EPS 1e-5f
#define NOUT 2338   // 2048+256+32+1+1 output cols per batch row

typedef __bf16 bf16x8 __attribute__((ext_vector_type(8)));
typedef float f32x4 __attribute__((ext_vector_type(4)));
typedef unsigned short u16;

__device__ __forceinline__ u16 f2bf_bits(float f) {
  uint32_t u = __builtin_bit_cast(uint32_t, f);
  u += 0x7FFFu + ((u >> 16) & 1u);   // RNE
  return (u16)(u >> 16);
}

__device__ __forceinline__ uint32_t pack2(float lo, float hi) {
  return (uint32_t)f2bf_bits(lo) | ((uint32_t)f2bf_bits(hi) << 16);
}

// ---------------- kernel 0: x [256][3008] f32 -> bf16, packed in MFMA B-frag tile order
// XBp[ks][kb][m][e] : ks in [0,94), kb in [0,4), m in [0,256), e in [0,8)
// element = x[m][ks*32 + kb*8 + e]; each k-step tile (8192 elems = 16KB) is contiguous.
__global__ __launch_bounds__(256) void cvt_pack_kernel(const float* __restrict__ x,
                                                       u16* __restrict__ xbp) {
  const int i = blockIdx.x * 256 + threadIdx.x;   // 96256 total
  const int ks = i >> 10;
  const int rem = i & 1023;
  const int kb = rem >> 8;
  const int m = rem & 255;
  const f32x4* src = (const f32x4*)(x + (size_t)m * 3008 + ks * 32 + kb * 8);
  f32x4 a = src[0], b = src[1];
  uint4 o;
  o.x = pack2(a.x, a.y);
  o.y = pack2(a.z, a.w);
  o.z = pack2(b.x, b.y);
  o.w = pack2(b.z, b.w);
  ((uint4*)xbp)[i] = o;   // write offset matches ((ks*4+kb)*256+m)*16B
}

// ---------------- kernel 1: leaf GEMM  h[tg][b] = sum_n gW[tg][n]*x[b][n] + gb[tg]
// C [20480 x 256] = W[20480 x 3008] * X^T.  16x16x32 bf16 MFMA.
// block = 256 thr (4 waves). Wave w: row-group rg=w>>1 (16 rows), m-half mh=w&1 (8 m-tiles).
// Block covers 32 rows x full 256 batch. Grid = 640.
__global__ __launch_bounds__(256) void gemm_leaf(const float* __restrict__ W,
                                                 const float* __restrict__ gb,
                                                 const u16* __restrict__ XBp,
                                                 float* __restrict__ hout) {
  __shared__ __align__(16) u16 xl[8192];   // one 16KB X tile [kb][m][e]
  const int tid = threadIdx.x;
  const int w = tid >> 6;
  const int lane = tid & 63;
  const int rg = w >> 1;          // row-group 0..1
  const int mh = w & 1;           // m-half 0..1
  const int lquad = lane >> 4;    // k-group 0..3
  const int lmod = lane & 15;
  const int n0 = blockIdx.x * 32;
  const int arow = n0 + rg * 16 + lmod;

  f32x4 acc[8];
#pragma unroll
  for (int i = 0; i < 8; ++i) acc[i] = (f32x4){0.f, 0.f, 0.f, 0.f};

  const float* wp = W + (size_t)arow * 3008 + lquad * 8;
  const int ldsbase = lquad * 2048 + mh * 1024 + lmod * 8;  // u16 elems

  // stage tile ks: 16KB contiguous, 4 coalesced 1KB chunks per wave
#define STAGE(ks)                                                                       \
  {                                                                                     \
    _Pragma("unroll")                                                                   \
    for (int p = 0; p < 4; ++p) {                                                       \
      const int c = (w * 4 + p) * 64;                                                   \
      const u16* src = XBp + (size_t)(ks) * 8192 + (size_t)(c + lane) * 8;              \
      u16* dst = xl + (size_t)c * 8;                                                    \
      __builtin_amdgcn_global_load_lds((const __attribute__((address_space(1))) void*)src, \
                                       (__attribute__((address_space(3))) void*)dst,    \
                                       16, 0, 0);                                       \
    }                                                                                   \
  }

  // prologue
  STAGE(0);
  const f32x4* ap0 = (const f32x4*)(wp);
  f32x4 wa = __builtin_nontemporal_load(ap0);
  f32x4 wb = __builtin_nontemporal_load(ap0 + 1);

  for (int ks = 0; ks < 94; ++ks) {
    __syncthreads();   // drains STAGE(ks) + current W loads (vmcnt 0)

    // prefetch next W fragment (stays in flight across the raw barrier below)
    f32x4 na, nb;
    if (ks < 93) {
      const f32x4* ap = (const f32x4*)(wp + (ks + 1) * 32);
      na = __builtin_nontemporal_load(ap);
      nb = __builtin_nontemporal_load(ap + 1);
    }

    // convert current W row slice to bf16 A-fragment
    union { u16 u[8]; bf16x8 v; } af;
    af.u[0] = f2bf_bits(wa.x); af.u[1] = f2bf_bits(wa.y);
    af.u[2] = f2bf_bits(wa.z); af.u[3] = f2bf_bits(wa.w);
    af.u[4] = f2bf_bits(wb.x); af.u[5] = f2bf_bits(wb.y);
    af.u[6] = f2bf_bits(wb.z); af.u[7] = f2bf_bits(wb.w);

#pragma unroll
    for (int j = 0; j < 8; ++j) {
      const bf16x8 bfrag = *(const bf16x8*)(xl + ldsbase + j * 128);
      acc[j] = __builtin_amdgcn_mfma_f32_16x16x32_bf16(af.v, bfrag, acc[j], 0, 0, 0);
    }

    // "reads done" barrier WITHOUT vmcnt drain: W prefetch stays in flight
    asm volatile("s_waitcnt lgkmcnt(0)" ::: "memory");
    __builtin_amdgcn_sched_barrier(0);
    __builtin_amdgcn_s_barrier();
    __builtin_amdgcn_sched_barrier(0);

    if (ks < 93) STAGE(ks + 1);
    wa = na; wb = nb;
  }
#undef STAGE

  // store: D row = n0 + rg*16 + lquad*4 + r, col = (mh*8+j)*16 + lmod
  const int r0 = n0 + rg * 16 + lquad * 4;
  float gb4[4];
#pragma unroll
  for (int r2 = 0; r2 < 4; ++r2) gb4[r2] = gb[r0 + r2];
#pragma unroll
  for (int j = 0; j < 8; ++j) {
    const int col = (mh * 8 + j) * 16 + lmod;
#pragma unroll
    for (int r2 = 0; r2 < 4; ++r2) {
      hout[(size_t)(r0 + r2) * 256 + col] = acc[j][r2] + gb4[r2];
    }
  }
}

// ---------------- per-level kernel: one term per block, batch = 256 threads
__global__ __launch_bounds__(256) void level_kernel(
    const float* __restrict__ yin, const float* __restrict__ w,
    const float* __restrict__ bia, const float* __restrict__ gam,
    const float* __restrict__ bet, const float* __restrict__ p,
    const float* __restrict__ q, const float* __restrict__ r,
    const float* __restrict__ s, float* __restrict__ yout,
    float* __restrict__ out, int inl, int off) {
  const int t = blockIdx.x;
  const int b = threadIdx.x;
  __shared__ float wls[6 * 192];
  __shared__ float part[4][12];
  __shared__ float stats[12];  // mean[6], rstd[6]
  const float* wt = w + (size_t)t * 6 * inl;
  for (int i = b; i < 6 * inl; i += 256) wls[i] = wt[i];
  __syncthreads();

  float z[6];
#pragma unroll
  for (int h = 0; h < 6; ++h) z[h] = bia[t * 6 + h];
  const float* yp = yin + (size_t)t * inl * 256 + b;
  for (int i = 0; i < inl; ++i) {
    float v = yp[(size_t)i * 256];
#pragma unroll
    for (int h = 0; h < 6; ++h) z[h] = fmaf(v, wls[h * inl + i], z[h]);
  }
#pragma unroll
  for (int h = 0; h < 6; ++h) z[h] = tanhf(z[h]);

  float sm[6], sq[6];
#pragma unroll
  for (int h = 0; h < 6; ++h) { sm[h] = z[h]; sq[h] = z[h] * z[h]; }
#pragma unroll
  for (int o = 32; o > 0; o >>= 1) {
#pragma unroll
    for (int h = 0; h < 6; ++h) {
      sm[h] += __shfl_down(sm[h], o);
      sq[h] += __shfl_down(sq[h], o);
    }
  }
  const int lane = b & 63, wvi = b >> 6;
  if (lane == 0) {
#pragma unroll
    for (int h = 0; h < 6; ++h) { part[wvi][h] = sm[h]; part[wvi][6 + h] = sq[h]; }
  }
  __syncthreads();
  if (b < 6) {
    float msum = part[0][b] + part[1][b] + part[2][b] + part[3][b];
    float qsum = part[0][6 + b] + part[1][6 + b] + part[2][6 + b] + part[3][6 + b];
    float m = msum * (1.f / 256.f);
    float var = qsum * (1.f / 256.f) - m * m;
    stats[b] = m;
    stats[6 + b] = rsqrtf(var + EPS);
  }
  __syncthreads();

  float a = q[t];
#pragma unroll
  for (int h = 0; h < 6; ++h) {
    float yy = (z[h] - stats[h]) * stats[6 + h] * gam[t * 6 + h] + bet[t * 6 + h];
    yout[((size_t)t * 6 + h) * 256 + b] = yy;
    a = fmaf(yy, p[t * 6 + h], a);
  }
  out[(size_t)b * NOUT + off + t] = tanhf(a) * r[t] + s[t];
}

// ---------------- final head
__global__ __launch_bounds__(256) void final_kernel(
    const float* __restrict__ y3, const float* __restrict__ fw,
    const float* __restrict__ fb, const float* __restrict__ fg,
    const float* __restrict__ fe, const float* __restrict__ pw,
    const float* __restrict__ pb, const float* __restrict__ rw,
    const float* __restrict__ rb, float* __restrict__ out) {
  const int b = threadIdx.x;
  __shared__ float part[4][24];
  __shared__ float stats[24];
  float yr[6];
#pragma unroll
  for (int h = 0; h < 6; ++h) yr[h] = y3[h * 256 + b];
  float z[12];
#pragma unroll
  for (int j = 0; j < 12; ++j) {
    float a = fb[j];
#pragma unroll
    for (int h = 0; h < 6; ++h) a = fmaf(yr[h], fw[j * 6 + h], a);
    z[j] = tanhf(a);
  }
  float sm[12], sq[12];
#pragma unroll
  for (int j = 0; j < 12; ++j) { sm[j] = z[j]; sq[j] = z[j] * z[j]; }
#pragma unroll
  for (int o = 32; o > 0; o >>= 1) {
#pragma unroll
    for (int j = 0; j < 12; ++j) {
      sm[j] += __shfl_down(sm[j], o);
      sq[j] += __shfl_down(sq[j], o);
    }
  }
  const int lane = b & 63, wvi = b >> 6;
  if (lane == 0) {
#pragma unroll
    for (int j = 0; j < 12; ++j) { part[wvi][j] = sm[j]; part[wvi][12 + j] = sq[j]; }
  }
  __syncthreads();
  if (b < 12) {
    float msum = part[0][b] + part[1][b] + part[2][b] + part[3][b];
    float qsum = part[0][12 + b] + part[1][12 + b] + part[2][12 + b] + part[3][12 + b];
    float m = msum * (1.f / 256.f);
    float var = qsum * (1.f / 256.f) - m * m;
    stats[b] = m;
    stats[12 + b] = rsqrtf(var + EPS);
  }
  __syncthreads();
  float a = pb[0];
#pragma unroll
  for (int j = 0; j < 12; ++j) {
    float of = (z[j] - stats[j]) * stats[12 + j] * fg[j] + fe[j];
    a = fmaf(of, pw[j], a);
  }
  out[(size_t)b * NOUT + 2337] = tanhf(a) * rw[0] + rb[0];
}

extern "C" void kernel_launch(void* const* d_in, const int* in_sizes, int n_in,
                              void* d_out, int out_size, void* d_ws, size_t ws_size,
                              hipStream_t stream) {
  const float* x  = (const float*)d_in[0];
  const float* gW = (const float*)d_in[1];
  const float* gb = (const float*)d_in[2];
  float* out = (float*)d_out;

  char* wsb = (char*)d_ws;
  u16* XBp = (u16*)wsb;                              // 256*3008 bf16 = 1,540,096 B (packed)
  float* h0 = (float*)(wsb + 1540096);               // [20480][256]
  float* y0 = h0 + (size_t)20480 * 256;              // [12288][256]
  float* y1 = y0 + (size_t)12288 * 256;              // [1536][256]
  float* y2 = y1 + (size_t)1536 * 256;               // [192][256]
  float* y3 = y2 + (size_t)192 * 256;                // [6][256]

  cvt_pack_kernel<<<dim3(376), dim3(256), 0, stream>>>(x, XBp);
  gemm_leaf<<<dim3(640), dim3(256), 0, stream>>>(gW, gb, XBp, h0);

#define LV(base, yin, yout, inl, off, grid)                                           \
  level_kernel<<<dim3(grid), dim3(256), 0, stream>>>(                                 \
      yin, (const float*)d_in[base], (const float*)d_in[base + 1],                    \
      (const float*)d_in[base + 2], (const float*)d_in[base + 3],                     \
      (const float*)d_in[base + 4], (const float*)d_in[base + 5],                     \
      (const float*)d_in[base + 6], (const float*)d_in[base + 7], yout, out, inl, off)

  LV(3,  h0, y0, 10,  0,    2048);
  LV(11, y0, y1, 48,  2048, 256);
  LV(19, y1, y2, 48,  2304, 32);
  LV(27, y2, y3, 192, 2336, 1);
#undef LV

  final_kernel<<<dim3(1), dim3(256), 0, stream>>>(
      y3, (const float*)d_in[35], (const float*)d_in[36], (const float*)d_in[37],
      (const float*)d_in[38], (const float*)d_in[39], (const float*)d_in[40],
      (const float*)d_in[41], (const float*)d_in[42], out);
}